// Round 17
// baseline (350.072 us; speedup 1.0000x reference)
//
#include <hip/hip_runtime.h>

#define B_ 8
#define C_ 96
#define CP_ 104   // padded channels: 208 B/point; pad never read by MFMA (k<96)
#define M_ 4096
#define K_ 9
#define NSPLIT 4
#define NPART (M_ / NSPLIT)   // 1024 neighbors per block
#define NTILES (NPART / 64)   // 16 tiles

typedef _Float16 f16x8 __attribute__((ext_vector_type(8)));
typedef float f32x4 __attribute__((ext_vector_type(4)));

// full list-insert (assumes dv < tmax already checked)
#define INSERT(dv, nv) do {                                                   \
    const int pz_ = tpos;                                                     \
    _Pragma("unroll")                                                         \
    for (int k_ = 0; k_ < K_; ++k_) if (k_ == pz_) { tv[k_] = (dv); ti[k_] = (nv); } \
    float mx_ = tv[0]; int mp_ = 0;                                           \
    _Pragma("unroll")                                                         \
    for (int k_ = 1; k_ < K_; ++k_) if (tv[k_] > mx_) { mx_ = tv[k_]; mp_ = k_; } \
    tmax = mx_; tpos = mp_;                                                   \
  } while (0)

// ---------------------------------------------------------------------------
// prep1: per-point squared norm + fp16 split (hi = f16(x), lo = f16(x - hi))
// written point-major [B][M][CP_]. (unchanged, proven)
// ---------------------------------------------------------------------------
__global__ __launch_bounds__(256) void prep1_kernel(
    const float* __restrict__ x, float* __restrict__ sq,
    unsigned short* __restrict__ xhi, unsigned short* __restrict__ xlo) {
  __shared__ float Xt[C_][64];
  const int b = blockIdx.y, m0 = blockIdx.x * 64, tid = threadIdx.x;
  const float* xb = x + (size_t)b * C_ * M_;
  for (int i = tid; i < C_ * 16; i += 256) {
    int c = i >> 4, j4 = (i & 15) << 2;
    *(float4*)&Xt[c][j4] = *(const float4*)&xb[(size_t)c * M_ + m0 + j4];
  }
  __syncthreads();
  if (tid < 64) {
    float s = 0.f;
#pragma unroll
    for (int c = 0; c < C_; ++c) { float v = Xt[c][tid]; s += v * v; }
    sq[b * M_ + m0 + tid] = s;
  }
  const int p = tid & 63, part = tid >> 6;  // thread owns point p, 24 channels
  union { unsigned short u[24]; uint4 q[3]; } hb, lb;
#pragma unroll
  for (int i = 0; i < 24; ++i) {
    float v = Xt[part * 24 + i][p];
    _Float16 h = (_Float16)v;
    _Float16 l = (_Float16)(v - (float)h);
    hb.u[i] = __builtin_bit_cast(unsigned short, h);
    lb.u[i] = __builtin_bit_cast(unsigned short, l);
  }
  size_t base = ((size_t)b * M_ + m0 + p) * CP_ + part * 24;
#pragma unroll
  for (int i = 0; i < 3; ++i) {
    *(uint4*)&xhi[base + i * 8] = hb.q[i];
    *(uint4*)&xlo[base + i * 8] = lb.q[i];
  }
}

// ---------------------------------------------------------------------------
// knn v8 = r16's race-free skeleton (register round-trip staging, two
// barriers/tile, swapped-operand MFMA, selection on accumulators) with:
//   (1) BRANCH-FREE top-2-of-tile selection: 11 straight-line VALU ops per
//       candidate, no divergent pushes, no mid-tile INSERTs. Exact: tmax is
//       constant within a tile, so cnt (passes vs tile-entry t0) <= 2 ==>
//       top-2 holds all insertable candidates; wave-any cnt>2 falls back to
//       the exact sequential re-scan of the 16 stored d values.
//   (2) NSPLIT=4 -> grid 2048 -> up to 5 blocks/CU (LDS-capped).
// ---------------------------------------------------------------------------
__global__ __launch_bounds__(256, 3) void knn_kernel(
    const unsigned short* __restrict__ xhi, const unsigned short* __restrict__ xlo,
    const float* __restrict__ sq, float* __restrict__ pv, int* __restrict__ pi) {
  __shared__ struct { unsigned short bhi[64 * CP_]; unsigned short blo[64 * CP_]; } S; // 26624 B
  __shared__ float sqc[64];
  const int b = blockIdx.y, r0 = blockIdx.x * 64, h = blockIdx.z;
  const int tid = threadIdx.x;
  const int lane = tid & 63, w = tid >> 6;
  const int fp = lane & 15, kg = lane >> 4;
  const size_t bm = (size_t)b * M_;
  const int nbeg = h * NPART;

  // resident QUERY fragments (B operand): query q = r0 + w*16 + fp
  f16x8 qhi[3], qlo[3];
#pragma unroll
  for (int kt = 0; kt < 3; ++kt) {
    size_t off = (bm + r0 + w * 16 + fp) * CP_ + kt * 32 + kg * 8;
    qhi[kt] = *(const f16x8*)&xhi[off];
    qlo[kt] = *(const f16x8*)&xlo[off];
  }

  float tv[K_]; int ti[K_]; float tmax = 3.4e38f; int tpos = 0;
#pragma unroll
  for (int k = 0; k < K_; ++k) { tv[k] = 3.4e38f; ti[k] = 0; }

  // prefetch registers: 832 uint4 per array / 256 threads = 3 + (tid<64 ? 1:0)
  uint4 ph0, ph1, ph2, ph3, pl0, pl1, pl2, pl3;
  float sqreg = 0.f;
  auto gload = [&](int n0) {           // global -> private regs (no race class)
    const uint4* gh = (const uint4*)(xhi + (bm + n0) * CP_);
    const uint4* gl = (const uint4*)(xlo + (bm + n0) * CP_);
    ph0 = gh[tid]; ph1 = gh[tid + 256]; ph2 = gh[tid + 512];
    pl0 = gl[tid]; pl1 = gl[tid + 256]; pl2 = gl[tid + 512];
    if (tid < 64) {
      ph3 = gh[tid + 768]; pl3 = gl[tid + 768];
      sqreg = sq[bm + n0 + tid];
    }
  };
  auto swrite = [&]() {                // regs -> LDS (between the barrier pair)
    uint4* dh = (uint4*)S.bhi; uint4* dl = (uint4*)S.blo;
    dh[tid] = ph0; dh[tid + 256] = ph1; dh[tid + 512] = ph2;
    dl[tid] = pl0; dl[tid + 256] = pl1; dl[tid + 512] = pl2;
    if (tid < 64) { dh[tid + 768] = ph3; dl[tid + 768] = pl3; sqc[tid] = sqreg; }
  };

  gload(nbeg);
  for (int t = 0; t < NTILES; ++t) {
    const int n0 = nbeg + t * 64;
    __syncthreads();                   // all lanes done READING tile t-1 from S
    swrite();
    if (t < NTILES - 1) gload(n0 + 64);  // next tile -> regs, hidden under compute
    __syncthreads();                   // tile t visible in S

    // branch-free top-2-of-tile tracker (exact with cnt<=2; see header)
    const float t0 = tmax;             // tile-entry threshold (const this tile)
    float s0 = 3.4e38f, s1 = 3.4e38f;
    int i0 = 0, i1 = 0, cnt = 0;
    float dstore[16];                  // static-indexed (loops fully unrolled)

#pragma unroll
    for (int rs = 0; rs < 4; ++rs) {
      // A fragment: neighbor rows rs*16+fp, k-slice kg*8 from LDS
      f16x8 nh[3], nl[3];
#pragma unroll
      for (int kt = 0; kt < 3; ++kt) {
        int boff = (rs * 16 + fp) * CP_ + kt * 32 + kg * 8;
        nh[kt] = *(const f16x8*)&S.bhi[boff];
        nl[kt] = *(const f16x8*)&S.blo[boff];
      }
      f32x4 acc = {0.f, 0.f, 0.f, 0.f};
#pragma unroll
      for (int kt = 0; kt < 3; ++kt) {
        acc = __builtin_amdgcn_mfma_f32_16x16x32_f16(nh[kt], qhi[kt], acc, 0, 0, 0);
        acc = __builtin_amdgcn_mfma_f32_16x16x32_f16(nh[kt], qlo[kt], acc, 0, 0, 0);
        acc = __builtin_amdgcn_mfma_f32_16x16x32_f16(nl[kt], qhi[kt], acc, 0, 0, 0);
      }
      // D: col=lane&15 (our query), row=(lane>>4)*4+r (neighbor in chunk rs)
#pragma unroll
      for (int r = 0; r < 4; ++r) {
        const int nrow = rs * 16 + kg * 4 + r;
        const int n = n0 + nrow;
        const float d = sqc[nrow] - 2.f * acc[r];
        dstore[rs * 4 + r] = d;
        cnt += (d < t0) ? 1 : 0;
        const bool c0 = d < s0;
        const float mx = fmaxf(s0, d);
        const int i0o = i0;
        s0 = fminf(s0, d);
        i0 = c0 ? n : i0;
        const int cmx = c0 ? i0o : n;  // index of mx
        const bool c1 = mx < s1;
        s1 = fminf(s1, mx);
        i1 = c1 ? cmx : i1;
      }
    }

    if (__any(cnt > 2)) {
      // exact fallback: sequential re-scan of stored distances (all lanes)
#pragma unroll
      for (int j = 0; j < 16; ++j) {
        const float d = dstore[j];
        if (d < tmax) {
          const int n = n0 + (j >> 2) * 16 + kg * 4 + (j & 3);
          INSERT(d, n);
        }
      }
    } else {
      // drain top-2 (s0 <= s1), recheck each against evolving tmax
      if (s0 < tmax) { INSERT(s0, i0); }
      if (s1 < tmax) { INSERT(s1, i1); }
    }
  }

  // ---- merge 4 lane-lists (kg) per query row -> per-part top-9 -> ws ----
  __syncthreads();                     // tile reads done; reuse S as merge buf
  float* mv = (float*)&S;
  int*   mi = (int*)((char*)&S + 64 * 37 * 4);
  const int qrow = w * 16 + fp;
#pragma unroll
  for (int k = 0; k < K_; ++k) {
    mv[qrow * 37 + kg * K_ + k] = tv[k];
    mi[qrow * 37 + kg * K_ + k] = ti[k];
  }
  __syncthreads();
  if (tid < 64) {
    float fv[K_]; int fi[K_];
    float mx = 3.4e38f; int mp = 0;
#pragma unroll
    for (int k = 0; k < K_; ++k) { fv[k] = 3.4e38f; fi[k] = 0; }
    for (int s = 0; s < 36; ++s) {
      float v = mv[tid * 37 + s]; int id = mi[tid * 37 + s];
      if (v < mx) {
#pragma unroll
        for (int k = 0; k < K_; ++k) if (k == mp) { fv[k] = v; fi[k] = id; }
        float m2 = fv[0]; int p2 = 0;
#pragma unroll
        for (int k = 1; k < K_; ++k) if (fv[k] > m2) { m2 = fv[k]; p2 = k; }
        mx = m2; mp = p2;
      }
    }
    size_t base = ((size_t)h * B_ * M_ + bm + r0 + tid) * K_;
#pragma unroll
    for (int k = 0; k < K_; ++k) { pv[base + k] = fv[k]; pi[base + k] = fi[k]; }
  }
}

// ---------------------------------------------------------------------------
// knn_merge: top-9 of the four quarter-space top-9 lists -> idxw.
// ---------------------------------------------------------------------------
__global__ __launch_bounds__(256) void knn_merge_kernel(
    const float* __restrict__ pv, const int* __restrict__ pi,
    int* __restrict__ idxw) {
  const int g = blockIdx.x * 256 + threadIdx.x;        // 0 .. B_*M_-1
  float tv[K_]; int ti[K_]; float tmax = 3.4e38f; int tpos = 0;
#pragma unroll
  for (int k = 0; k < K_; ++k) { tv[k] = 3.4e38f; ti[k] = 0; }
#pragma unroll
  for (int h = 0; h < NSPLIT; ++h) {
    const float* vs = pv + ((size_t)h * B_ * M_ + g) * K_;
    const int*   is = pi + ((size_t)h * B_ * M_ + g) * K_;
#pragma unroll
    for (int s = 0; s < K_; ++s) {
      float d = vs[s];
      if (d < tmax) { int n = is[s]; INSERT(d, n); }
    }
  }
#pragma unroll
  for (int k = 0; k < K_; ++k) idxw[(size_t)g * K_ + k] = ti[k];
}

// ---------------------------------------------------------------------------
// prep2: P/Q projection GEMM (runs AFTER knn; reuses the dead xhi/xlo region).
//   P[m] = x_m @ (W1[0:C] - W1[C:2C]) + b1,  Q[m] = x_m @ W1[C:2C]
// ---------------------------------------------------------------------------
__global__ __launch_bounds__(256) void prep2_kernel(
    const float* __restrict__ x, const float* __restrict__ W1,
    const float* __restrict__ b1, float* __restrict__ P, float* __restrict__ Q) {
  __shared__ float Xt[C_][64];
  __shared__ float Wt[C_][64];
  const int b = blockIdx.y, m0 = blockIdx.x * 64;
  const int tid = threadIdx.x;
  const float* xb = x + (size_t)b * C_ * M_;

  for (int i = tid; i < C_ * 16; i += 256) {
    int c = i >> 4, j4 = (i & 15) << 2;
    *(float4*)&Xt[c][j4] = *(const float4*)&xb[(size_t)c * M_ + m0 + j4];
  }

  const int ty = tid >> 4, tx = tid & 15;
  for (int t = 0; t < 3; ++t) {
    const int u0 = t * 64;
    __syncthreads();
    for (int i = tid; i < C_ * 64; i += 256) {
      int cin = i >> 6, j = i & 63;
      int u = u0 + j;
      float wv;
      if (u < C_) wv = W1[cin * C_ + u] - W1[(C_ + cin) * C_ + u];
      else        wv = W1[(C_ + cin) * C_ + (u - C_)];
      Wt[cin][j] = wv;
    }
    __syncthreads();
    float acc[4][4] = {};
#pragma unroll 8
    for (int c = 0; c < C_; ++c) {
      float4 rr = *(const float4*)&Xt[c][ty << 2];
      float4 ww = *(const float4*)&Wt[c][tx << 2];
      acc[0][0] += rr.x * ww.x; acc[0][1] += rr.x * ww.y; acc[0][2] += rr.x * ww.z; acc[0][3] += rr.x * ww.w;
      acc[1][0] += rr.y * ww.x; acc[1][1] += rr.y * ww.y; acc[1][2] += rr.y * ww.z; acc[1][3] += rr.y * ww.w;
      acc[2][0] += rr.z * ww.x; acc[2][1] += rr.z * ww.y; acc[2][2] += rr.z * ww.z; acc[2][3] += rr.z * ww.w;
      acc[3][0] += rr.w * ww.x; acc[3][1] += rr.w * ww.y; acc[3][2] += rr.w * ww.z; acc[3][3] += rr.w * ww.w;
    }
#pragma unroll
    for (int i = 0; i < 4; ++i) {
      int m = m0 + (ty << 2) + i;
      size_t base = ((size_t)b * M_ + m) * C_;
#pragma unroll
      for (int j = 0; j < 4; ++j) {
        int u = u0 + (tx << 2) + j;
        float v = acc[i][j];
        if (u < C_) P[base + u] = v + b1[u];
        else        Q[base + (u - C_)] = v;
      }
    }
  }
}

// ---------------------------------------------------------------------------
// edge_mlp: g[m] = mean_k LReLU(P[m] + Q[idx[m,k]]); out = relu(g @ W2 + b2).
// ---------------------------------------------------------------------------
__global__ __launch_bounds__(256) void edge_mlp_kernel(
    const float* __restrict__ P, const float* __restrict__ Q,
    const int* __restrict__ idxw, const float* __restrict__ W2,
    const float* __restrict__ b2, float* __restrict__ out) {
  __shared__ float g_l[C_][64];
  __shared__ float W2t[C_ * C_];
  const int b = blockIdx.y, m0 = blockIdx.x * 64;
  const int tid = threadIdx.x;

  for (int i = tid; i < (C_ * C_) / 4; i += 256)
    *(float4*)&W2t[i * 4] = *(const float4*)&W2[i * 4];

  const int ml = tid & 63, cg = tid >> 6;
  const int m = m0 + ml;
  const float* prow = P + ((size_t)b * M_ + m) * C_ + cg * 24;
  float pr[24];
#pragma unroll
  for (int t = 0; t < 24; t += 4) {
    float4 v = *(const float4*)(prow + t);
    pr[t] = v.x; pr[t + 1] = v.y; pr[t + 2] = v.z; pr[t + 3] = v.w;
  }
  float gacc[24] = {};
  const int* irow = idxw + ((size_t)b * M_ + m) * K_;
#pragma unroll
  for (int k = 0; k < K_; ++k) {
    int j = irow[k];
    const float* qrow = Q + ((size_t)b * M_ + j) * C_ + cg * 24;
#pragma unroll
    for (int t = 0; t < 24; t += 4) {
      float4 qv = *(const float4*)(qrow + t);
      float h;
      h = pr[t + 0] + qv.x; gacc[t + 0] += (h >= 0.f) ? h : 0.01f * h;
      h = pr[t + 1] + qv.y; gacc[t + 1] += (h >= 0.f) ? h : 0.01f * h;
      h = pr[t + 2] + qv.z; gacc[t + 2] += (h >= 0.f) ? h : 0.01f * h;
      h = pr[t + 3] + qv.w; gacc[t + 3] += (h >= 0.f) ? h : 0.01f * h;
    }
  }
#pragma unroll
  for (int t = 0; t < 24; ++t) g_l[cg * 24 + t][ml] = gacc[t] * (1.f / 9.f);
  __syncthreads();

  const int ty = tid >> 4, tx = tid & 15;
  float acc2[4][6] = {};
#pragma unroll 4
  for (int c = 0; c < C_; ++c) {
    float4 rr = *(const float4*)&g_l[c][ty << 2];
    float2 wa = *(const float2*)&W2t[c * C_ + tx * 6];
    float2 wb = *(const float2*)&W2t[c * C_ + tx * 6 + 2];
    float2 wc = *(const float2*)&W2t[c * C_ + tx * 6 + 4];
    float rv[4] = {rr.x, rr.y, rr.z, rr.w};
    float wv[6] = {wa.x, wa.y, wb.x, wb.y, wc.x, wc.y};
#pragma unroll
    for (int i = 0; i < 4; ++i)
#pragma unroll
      for (int j = 0; j < 6; ++j) acc2[i][j] += rv[i] * wv[j];
  }
#pragma unroll
  for (int i = 0; i < 4; ++i) {
    int mm = m0 + (ty << 2) + i;
#pragma unroll
    for (int j = 0; j < 6; ++j) {
      int u = tx * 6 + j;
      float v = acc2[i][j] + b2[u];
      v = fmaxf(v, 0.f);
      out[((size_t)b * C_ + u) * M_ + mm] = v;
    }
  }
}

extern "C" void kernel_launch(void* const* d_in, const int* in_sizes, int n_in,
                              void* d_out, int out_size, void* d_ws, size_t ws_size,
                              hipStream_t stream) {
  const float* x  = (const float*)d_in[0];
  const float* W1 = (const float*)d_in[1];
  const float* b1 = (const float*)d_in[2];
  const float* W2 = (const float*)d_in[3];
  const float* b2 = (const float*)d_in[4];
  float* out = (float*)d_out;

  // ws layout — peak 26,476,544 B (proven footprint; do NOT grow):
  //   [0,        131072)     sq
  //   [131072,   1310720)    idxw
  //   phase 1 (prep1+knn):   xhi [1310720, 8126464), xlo [8126464, 14942208)
  //                          pv  [14942208, 19660800), pi [19660800, 24379392)
  //   phase 2 (prep2+mlp):   P   [1310720, 13893632), Q  [13893632, 26476544)
  //   (P/Q alias the dead xhi/xlo/pv/pi regions; kernels are stream-ordered)
  char* ws = (char*)d_ws;
  float* sq  = (float*)ws;
  int* idxw  = (int*)(ws + 131072);
  unsigned short* xhi = (unsigned short*)(ws + 1310720);
  unsigned short* xlo = (unsigned short*)(ws + 8126464);
  float* pv = (float*)(ws + 14942208);
  int*   pi = (int*)(ws + 19660800);
  float* P = (float*)(ws + 1310720);
  float* Q = (float*)(ws + 13893632);

  dim3 blk(256);
  prep1_kernel<<<dim3(M_ / 64, B_), blk, 0, stream>>>(x, sq, xhi, xlo);
  knn_kernel<<<dim3(M_ / 64, B_, NSPLIT), blk, 0, stream>>>(xhi, xlo, sq, pv, pi);
  knn_merge_kernel<<<dim3(B_ * M_ / 256), blk, 0, stream>>>(pv, pi, idxw);
  prep2_kernel<<<dim3(M_ / 64, B_), blk, 0, stream>>>(x, W1, b1, P, Q);
  edge_mlp_kernel<<<dim3(M_ / 64, B_), blk, 0, stream>>>(P, Q, idxw, W2, b2, out);
}

// Round 20
// 278.628 us; speedup vs baseline: 1.2564x; 1.2564x over previous
//
#include <hip/hip_runtime.h>

#define B_ 8
#define C_ 96
#define CP_ 104   // padded channels: 208 B/point; pad never read by MFMA (k<96)
#define M_ 4096
#define K_ 9
#define NSPLIT 2
#define NPART (M_ / NSPLIT)   // 2048 neighbors per block
#define NTILES (NPART / 64)   // 32 tiles

typedef _Float16 f16x8 __attribute__((ext_vector_type(8)));
typedef float f32x4 __attribute__((ext_vector_type(4)));

// full list-insert (assumes dv < tmax already checked)
#define INSERT(dv, nv) do {                                                   \
    const int pz_ = tpos;                                                     \
    _Pragma("unroll")                                                         \
    for (int k_ = 0; k_ < K_; ++k_) if (k_ == pz_) { tv[k_] = (dv); ti[k_] = (nv); } \
    float mx_ = tv[0]; int mp_ = 0;                                           \
    _Pragma("unroll")                                                         \
    for (int k_ = 1; k_ < K_; ++k_) if (tv[k_] > mx_) { mx_ = tv[k_]; mp_ = k_; } \
    tmax = mx_; tpos = mp_;                                                   \
  } while (0)

// ---------------------------------------------------------------------------
// prep1: per-point squared norm + fp16 split (hi = f16(x), lo = f16(x - hi))
// written point-major [B][M][CP_]. (unchanged, proven)
// ---------------------------------------------------------------------------
__global__ __launch_bounds__(256) void prep1_kernel(
    const float* __restrict__ x, float* __restrict__ sq,
    unsigned short* __restrict__ xhi, unsigned short* __restrict__ xlo) {
  __shared__ float Xt[C_][64];
  const int b = blockIdx.y, m0 = blockIdx.x * 64, tid = threadIdx.x;
  const float* xb = x + (size_t)b * C_ * M_;
  for (int i = tid; i < C_ * 16; i += 256) {
    int c = i >> 4, j4 = (i & 15) << 2;
    *(float4*)&Xt[c][j4] = *(const float4*)&xb[(size_t)c * M_ + m0 + j4];
  }
  __syncthreads();
  if (tid < 64) {
    float s = 0.f;
#pragma unroll
    for (int c = 0; c < C_; ++c) { float v = Xt[c][tid]; s += v * v; }
    sq[b * M_ + m0 + tid] = s;
  }
  const int p = tid & 63, part = tid >> 6;  // thread owns point p, 24 channels
  union { unsigned short u[24]; uint4 q[3]; } hb, lb;
#pragma unroll
  for (int i = 0; i < 24; ++i) {
    float v = Xt[part * 24 + i][p];
    _Float16 h = (_Float16)v;
    _Float16 l = (_Float16)(v - (float)h);
    hb.u[i] = __builtin_bit_cast(unsigned short, h);
    lb.u[i] = __builtin_bit_cast(unsigned short, l);
  }
  size_t base = ((size_t)b * M_ + m0 + p) * CP_ + part * 24;
#pragma unroll
  for (int i = 0; i < 3; ++i) {
    *(uint4*)&xhi[base + i * 8] = hb.q[i];
    *(uint4*)&xlo[base + i * 8] = lb.q[i];
  }
}

// ---------------------------------------------------------------------------
// knn = r16 VERBATIM (best passing config, 278 us total / knn 206 us).
//   - register round-trip staging (race-free within the kernel)
//   - two barriers/tile; swapped-operand MFMA; selection on accumulators
//   - per-tile cap-2 EXEC-MASKED push buffer
// ---------------------------------------------------------------------------
__global__ __launch_bounds__(256, 3) void knn_kernel(
    const unsigned short* __restrict__ xhi, const unsigned short* __restrict__ xlo,
    const float* __restrict__ sq, float* __restrict__ pv, int* __restrict__ pi) {
  __shared__ struct { unsigned short bhi[64 * CP_]; unsigned short blo[64 * CP_]; } S; // 26624 B
  __shared__ float sqc[64];
  const int b = blockIdx.y, r0 = blockIdx.x * 64, h = blockIdx.z;
  const int tid = threadIdx.x;
  const int lane = tid & 63, w = tid >> 6;
  const int fp = lane & 15, kg = lane >> 4;
  const size_t bm = (size_t)b * M_;
  const int nbeg = h * NPART;

  // resident QUERY fragments (B operand): query q = r0 + w*16 + fp
  f16x8 qhi[3], qlo[3];
#pragma unroll
  for (int kt = 0; kt < 3; ++kt) {
    size_t off = (bm + r0 + w * 16 + fp) * CP_ + kt * 32 + kg * 8;
    qhi[kt] = *(const f16x8*)&xhi[off];
    qlo[kt] = *(const f16x8*)&xlo[off];
  }

  float tv[K_]; int ti[K_]; float tmax = 3.4e38f; int tpos = 0;
#pragma unroll
  for (int k = 0; k < K_; ++k) { tv[k] = 3.4e38f; ti[k] = 0; }

  // prefetch registers: 832 uint4 per array / 256 threads = 3 + (tid<64 ? 1:0)
  uint4 ph0, ph1, ph2, ph3, pl0, pl1, pl2, pl3;
  float sqreg = 0.f;
  auto gload = [&](int n0) {           // global -> private regs (no race class)
    const uint4* gh = (const uint4*)(xhi + (bm + n0) * CP_);
    const uint4* gl = (const uint4*)(xlo + (bm + n0) * CP_);
    ph0 = gh[tid]; ph1 = gh[tid + 256]; ph2 = gh[tid + 512];
    pl0 = gl[tid]; pl1 = gl[tid + 256]; pl2 = gl[tid + 512];
    if (tid < 64) {
      ph3 = gh[tid + 768]; pl3 = gl[tid + 768];
      sqreg = sq[bm + n0 + tid];
    }
  };
  auto swrite = [&]() {                // regs -> LDS (between the barrier pair)
    uint4* dh = (uint4*)S.bhi; uint4* dl = (uint4*)S.blo;
    dh[tid] = ph0; dh[tid + 256] = ph1; dh[tid + 512] = ph2;
    dl[tid] = pl0; dl[tid + 256] = pl1; dl[tid + 512] = pl2;
    if (tid < 64) { dh[tid + 768] = ph3; dl[tid + 768] = pl3; sqc[tid] = sqreg; }
  };

  gload(nbeg);
  for (int t = 0; t < NTILES; ++t) {
    const int n0 = nbeg + t * 64;
    __syncthreads();                   // all lanes done READING tile t-1 from S
    swrite();
    if (t < NTILES - 1) gload(n0 + 64);  // next tile -> regs, hidden under compute
    __syncthreads();                   // tile t visible in S

    // per-tile cap-2 deferred-insert buffer (reset here, drained below)
    float b0d = 0.f, b1d = 0.f; int b0n = 0, b1n = 0, bcnt = 0;

#pragma unroll
    for (int rs = 0; rs < 4; ++rs) {
      // A fragment: neighbor rows rs*16+fp, k-slice kg*8 from LDS
      f16x8 nh[3], nl[3];
#pragma unroll
      for (int kt = 0; kt < 3; ++kt) {
        int boff = (rs * 16 + fp) * CP_ + kt * 32 + kg * 8;
        nh[kt] = *(const f16x8*)&S.bhi[boff];
        nl[kt] = *(const f16x8*)&S.blo[boff];
      }
      f32x4 acc = {0.f, 0.f, 0.f, 0.f};
#pragma unroll
      for (int kt = 0; kt < 3; ++kt) {
        acc = __builtin_amdgcn_mfma_f32_16x16x32_f16(nh[kt], qhi[kt], acc, 0, 0, 0);
        acc = __builtin_amdgcn_mfma_f32_16x16x32_f16(nh[kt], qlo[kt], acc, 0, 0, 0);
        acc = __builtin_amdgcn_mfma_f32_16x16x32_f16(nl[kt], qhi[kt], acc, 0, 0, 0);
      }
      // D: col=lane&15 (our query), row=(lane>>4)*4+r (neighbor in chunk rs)
#pragma unroll
      for (int r = 0; r < 4; ++r) {
        const int nrow = rs * 16 + kg * 4 + r;
        const float d = sqc[nrow] - 2.f * acc[r];   // broadcast LDS read
        if (d < tmax) {
          const int n = n0 + nrow;
          if (bcnt == 2) {
            if (b0d < tmax) INSERT(b0d, b0n);   // recheck: tmax may have tightened
            b0d = b1d; b0n = b1n;
            b1d = d;   b1n = n;
          } else if (bcnt == 1) {
            b1d = d; b1n = n; bcnt = 2;
          } else {
            b0d = d; b0n = n; bcnt = 1;
          }
        }
      }
    }
    // end-of-tile drain (recheck each; b0 is older)
    if (bcnt >= 1 && b0d < tmax) INSERT(b0d, b0n);
    if (bcnt == 2 && b1d < tmax) INSERT(b1d, b1n);
  }

  // ---- merge 4 lane-lists (kg) per query row -> per-part top-9 -> ws ----
  __syncthreads();                     // tile reads done; reuse S as merge buf
  float* mv = (float*)&S;
  int*   mi = (int*)((char*)&S + 64 * 37 * 4);
  const int qrow = w * 16 + fp;
#pragma unroll
  for (int k = 0; k < K_; ++k) {
    mv[qrow * 37 + kg * K_ + k] = tv[k];
    mi[qrow * 37 + kg * K_ + k] = ti[k];
  }
  __syncthreads();
  if (tid < 64) {
    float fv[K_]; int fi[K_];
    float mx = 3.4e38f; int mp = 0;
#pragma unroll
    for (int k = 0; k < K_; ++k) { fv[k] = 3.4e38f; fi[k] = 0; }
    for (int s = 0; s < 36; ++s) {
      float v = mv[tid * 37 + s]; int id = mi[tid * 37 + s];
      if (v < mx) {
#pragma unroll
        for (int k = 0; k < K_; ++k) if (k == mp) { fv[k] = v; fi[k] = id; }
        float m2 = fv[0]; int p2 = 0;
#pragma unroll
        for (int k = 1; k < K_; ++k) if (fv[k] > m2) { m2 = fv[k]; p2 = k; }
        mx = m2; mp = p2;
      }
    }
    size_t base = ((size_t)h * B_ * M_ + bm + r0 + tid) * K_;
#pragma unroll
    for (int k = 0; k < K_; ++k) { pv[base + k] = fv[k]; pi[base + k] = fi[k]; }
  }
}

// ---------------------------------------------------------------------------
// knn_merge: top-9 of the two half-space top-9 lists -> idxw.
// ---------------------------------------------------------------------------
__global__ __launch_bounds__(256) void knn_merge_kernel(
    const float* __restrict__ pv, const int* __restrict__ pi,
    int* __restrict__ idxw) {
  const int g = blockIdx.x * 256 + threadIdx.x;        // 0 .. B_*M_-1
  float tv[K_]; int ti[K_]; float tmax = 3.4e38f; int tpos = 0;
#pragma unroll
  for (int k = 0; k < K_; ++k) { tv[k] = 3.4e38f; ti[k] = 0; }
#pragma unroll
  for (int h = 0; h < NSPLIT; ++h) {
    const float* vs = pv + ((size_t)h * B_ * M_ + g) * K_;
    const int*   is = pi + ((size_t)h * B_ * M_ + g) * K_;
#pragma unroll
    for (int s = 0; s < K_; ++s) {
      float d = vs[s];
      if (d < tmax) { int n = is[s]; INSERT(d, n); }
    }
  }
#pragma unroll
  for (int k = 0; k < K_; ++k) idxw[(size_t)g * K_ + k] = ti[k];
}

// ---------------------------------------------------------------------------
// prep2: P/Q projection GEMM.
//   P[m] = x_m @ (W1[0:C] - W1[C:2C]) + b1,  Q[m] = x_m @ W1[C:2C]
// ---------------------------------------------------------------------------
__global__ __launch_bounds__(256) void prep2_kernel(
    const float* __restrict__ x, const float* __restrict__ W1,
    const float* __restrict__ b1, float* __restrict__ P, float* __restrict__ Q) {
  __shared__ float Xt[C_][64];
  __shared__ float Wt[C_][64];
  const int b = blockIdx.y, m0 = blockIdx.x * 64;
  const int tid = threadIdx.x;
  const float* xb = x + (size_t)b * C_ * M_;

  for (int i = tid; i < C_ * 16; i += 256) {
    int c = i >> 4, j4 = (i & 15) << 2;
    *(float4*)&Xt[c][j4] = *(const float4*)&xb[(size_t)c * M_ + m0 + j4];
  }

  const int ty = tid >> 4, tx = tid & 15;
  for (int t = 0; t < 3; ++t) {
    const int u0 = t * 64;
    __syncthreads();
    for (int i = tid; i < C_ * 64; i += 256) {
      int cin = i >> 6, j = i & 63;
      int u = u0 + j;
      float wv;
      if (u < C_) wv = W1[cin * C_ + u] - W1[(C_ + cin) * C_ + u];
      else        wv = W1[(C_ + cin) * C_ + (u - C_)];
      Wt[cin][j] = wv;
    }
    __syncthreads();
    float acc[4][4] = {};
#pragma unroll 8
    for (int c = 0; c < C_; ++c) {
      float4 rr = *(const float4*)&Xt[c][ty << 2];
      float4 ww = *(const float4*)&Wt[c][tx << 2];
      acc[0][0] += rr.x * ww.x; acc[0][1] += rr.x * ww.y; acc[0][2] += rr.x * ww.z; acc[0][3] += rr.x * ww.w;
      acc[1][0] += rr.y * ww.x; acc[1][1] += rr.y * ww.y; acc[1][2] += rr.y * ww.z; acc[1][3] += rr.y * ww.w;
      acc[2][0] += rr.z * ww.x; acc[2][1] += rr.z * ww.y; acc[2][2] += rr.z * ww.z; acc[2][3] += rr.z * ww.w;
      acc[3][0] += rr.w * ww.x; acc[3][1] += rr.w * ww.y; acc[3][2] += rr.w * ww.z; acc[3][3] += rr.w * ww.w;
    }
#pragma unroll
    for (int i = 0; i < 4; ++i) {
      int m = m0 + (ty << 2) + i;
      size_t base = ((size_t)b * M_ + m) * C_;
#pragma unroll
      for (int j = 0; j < 4; ++j) {
        int u = u0 + (tx << 2) + j;
        float v = acc[i][j];
        if (u < C_) P[base + u] = v + b1[u];
        else        Q[base + (u - C_)] = v;
      }
    }
  }
}

// ---------------------------------------------------------------------------
// edge_mlp: g[m] = mean_k LReLU(P[m] + Q[idx[m,k]]); out = relu(g @ W2 + b2).
// ---------------------------------------------------------------------------
__global__ __launch_bounds__(256) void edge_mlp_kernel(
    const float* __restrict__ P, const float* __restrict__ Q,
    const int* __restrict__ idxw, const float* __restrict__ W2,
    const float* __restrict__ b2, float* __restrict__ out) {
  __shared__ float g_l[C_][64];
  __shared__ float W2t[C_ * C_];
  const int b = blockIdx.y, m0 = blockIdx.x * 64;
  const int tid = threadIdx.x;

  for (int i = tid; i < (C_ * C_) / 4; i += 256)
    *(float4*)&W2t[i * 4] = *(const float4*)&W2[i * 4];

  const int ml = tid & 63, cg = tid >> 6;
  const int m = m0 + ml;
  const float* prow = P + ((size_t)b * M_ + m) * C_ + cg * 24;
  float pr[24];
#pragma unroll
  for (int t = 0; t < 24; t += 4) {
    float4 v = *(const float4*)(prow + t);
    pr[t] = v.x; pr[t + 1] = v.y; pr[t + 2] = v.z; pr[t + 3] = v.w;
  }
  float gacc[24] = {};
  const int* irow = idxw + ((size_t)b * M_ + m) * K_;
#pragma unroll
  for (int k = 0; k < K_; ++k) {
    int j = irow[k];
    const float* qrow = Q + ((size_t)b * M_ + j) * C_ + cg * 24;
#pragma unroll
    for (int t = 0; t < 24; t += 4) {
      float4 qv = *(const float4*)(qrow + t);
      float h;
      h = pr[t + 0] + qv.x; gacc[t + 0] += (h >= 0.f) ? h : 0.01f * h;
      h = pr[t + 1] + qv.y; gacc[t + 1] += (h >= 0.f) ? h : 0.01f * h;
      h = pr[t + 2] + qv.z; gacc[t + 2] += (h >= 0.f) ? h : 0.01f * h;
      h = pr[t + 3] + qv.w; gacc[t + 3] += (h >= 0.f) ? h : 0.01f * h;
    }
  }
#pragma unroll
  for (int t = 0; t < 24; ++t) g_l[cg * 24 + t][ml] = gacc[t] * (1.f / 9.f);
  __syncthreads();

  const int ty = tid >> 4, tx = tid & 15;
  float acc2[4][6] = {};
#pragma unroll 4
  for (int c = 0; c < C_; ++c) {
    float4 rr = *(const float4*)&g_l[c][ty << 2];
    float2 wa = *(const float2*)&W2t[c * C_ + tx * 6];
    float2 wb = *(const float2*)&W2t[c * C_ + tx * 6 + 2];
    float2 wc = *(const float2*)&W2t[c * C_ + tx * 6 + 4];
    float rv[4] = {rr.x, rr.y, rr.z, rr.w};
    float wv[6] = {wa.x, wa.y, wb.x, wb.y, wc.x, wc.y};
#pragma unroll
    for (int i = 0; i < 4; ++i)
#pragma unroll
      for (int j = 0; j < 6; ++j) acc2[i][j] += rv[i] * wv[j];
  }
#pragma unroll
  for (int i = 0; i < 4; ++i) {
    int mm = m0 + (ty << 2) + i;
#pragma unroll
    for (int j = 0; j < 6; ++j) {
      int u = tx * 6 + j;
      float v = acc2[i][j] + b2[u];
      v = fmaxf(v, 0.f);
      out[((size_t)b * C_ + u) * M_ + mm] = v;
    }
  }
}

extern "C" void kernel_launch(void* const* d_in, const int* in_sizes, int n_in,
                              void* d_out, int out_size, void* d_ws, size_t ws_size,
                              hipStream_t stream) {
  const float* x  = (const float*)d_in[0];
  const float* W1 = (const float*)d_in[1];
  const float* b1 = (const float*)d_in[2];
  const float* W2 = (const float*)d_in[3];
  const float* b2 = (const float*)d_in[4];
  float* out = (float*)d_out;

  // Workspace: PREFER FULLY-DISJOINT layout (44,826,624 B). Every post-timing
  // divergence (r3/r8/r12/r15/r18) occurred with P/Q aliased onto xhi/xlo/
  // pv/pi; the only never-flaking era (r1/r2) was alias-free. Mechanism:
  // stale-but-identical L2 lines are benign for disjoint buffers, but with
  // aliasing a stale line holds the OTHER buffer's bytes. If ws_size is too
  // small, fall back to the r16 aliased layout (host-side branch on ws_size
  // is deterministic across calls -> graph-safe).
  char* ws = (char*)d_ws;
  float* sq  = (float*)ws;                       // [0, 131072)
  int* idxw  = (int*)(ws + 131072);              // [131072, 1310720)
  unsigned short* xhi = (unsigned short*)(ws + 1310720);   // 6,815,744 B
  unsigned short* xlo = (unsigned short*)(ws + 8126464);   // 6,815,744 B
  float* pv; int* pi; float* P; float* Q;
  if (ws_size >= 44826624u) {
    pv = (float*)(ws + 14942208);                // 2,359,296 B
    pi = (int*)(ws + 17301504);                  // 2,359,296 B
    P  = (float*)(ws + 19660800);                // 12,582,912 B
    Q  = (float*)(ws + 32243712);                // 12,582,912 B  (end 44,826,624)
  } else {
    // r16 fallback (aliased; passed validation at 278 us, but flake-prone)
    pv = (float*)(ws + 14942208);
    pi = (int*)(ws + 19660800);
    P  = (float*)(ws + 1310720);
    Q  = (float*)(ws + 13893632);
  }

  dim3 blk(256);
  prep1_kernel<<<dim3(M_ / 64, B_), blk, 0, stream>>>(x, sq, xhi, xlo);
  knn_kernel<<<dim3(M_ / 64, B_, NSPLIT), blk, 0, stream>>>(xhi, xlo, sq, pv, pi);
  knn_merge_kernel<<<dim3(B_ * M_ / 256), blk, 0, stream>>>(pv, pi, idxw);
  prep2_kernel<<<dim3(M_ / 64, B_), blk, 0, stream>>>(x, W1, b1, P, Q);
  edge_mlp_kernel<<<dim3(M_ / 64, B_), blk, 0, stream>>>(P, Q, idxw, W2, b2, out);
}

// Round 22
// 277.035 us; speedup vs baseline: 1.2636x; 1.0057x over previous
//
#include <hip/hip_runtime.h>

#define B_ 8
#define C_ 96
#define CP_ 104   // padded channels: 208 B/point; pad never read by MFMA (k<96)
#define M_ 4096
#define K_ 9
#define NSPLIT 2
#define NPART (M_ / NSPLIT)   // 2048 neighbors per block
#define NTILES (NPART / 64)   // 32 tiles

typedef _Float16 f16x8 __attribute__((ext_vector_type(8)));
typedef float f32x4 __attribute__((ext_vector_type(4)));

// full list-insert (assumes dv < tmax already checked)
#define INSERT(dv, nv) do {                                                   \
    const int pz_ = tpos;                                                     \
    _Pragma("unroll")                                                         \
    for (int k_ = 0; k_ < K_; ++k_) if (k_ == pz_) { tv[k_] = (dv); ti[k_] = (nv); } \
    float mx_ = tv[0]; int mp_ = 0;                                           \
    _Pragma("unroll")                                                         \
    for (int k_ = 1; k_ < K_; ++k_) if (tv[k_] > mx_) { mx_ = tv[k_]; mp_ = k_; } \
    tmax = mx_; tpos = mp_;                                                   \
  } while (0)

// ---------------------------------------------------------------------------
// prep1: per-point squared norm + fp16 split (hi = f16(x), lo = f16(x - hi))
// written point-major [B][M][CP_]. (unchanged, proven)
// ---------------------------------------------------------------------------
__global__ __launch_bounds__(256) void prep1_kernel(
    const float* __restrict__ x, float* __restrict__ sq,
    unsigned short* __restrict__ xhi, unsigned short* __restrict__ xlo) {
  __shared__ float Xt[C_][64];
  const int b = blockIdx.y, m0 = blockIdx.x * 64, tid = threadIdx.x;
  const float* xb = x + (size_t)b * C_ * M_;
  for (int i = tid; i < C_ * 16; i += 256) {
    int c = i >> 4, j4 = (i & 15) << 2;
    *(float4*)&Xt[c][j4] = *(const float4*)&xb[(size_t)c * M_ + m0 + j4];
  }
  __syncthreads();
  if (tid < 64) {
    float s = 0.f;
#pragma unroll
    for (int c = 0; c < C_; ++c) { float v = Xt[c][tid]; s += v * v; }
    sq[b * M_ + m0 + tid] = s;
  }
  const int p = tid & 63, part = tid >> 6;  // thread owns point p, 24 channels
  union { unsigned short u[24]; uint4 q[3]; } hb, lb;
#pragma unroll
  for (int i = 0; i < 24; ++i) {
    float v = Xt[part * 24 + i][p];
    _Float16 h = (_Float16)v;
    _Float16 l = (_Float16)(v - (float)h);
    hb.u[i] = __builtin_bit_cast(unsigned short, h);
    lb.u[i] = __builtin_bit_cast(unsigned short, l);
  }
  size_t base = ((size_t)b * M_ + m0 + p) * CP_ + part * 24;
#pragma unroll
  for (int i = 0; i < 3; ++i) {
    *(uint4*)&xhi[base + i * 8] = hb.q[i];
    *(uint4*)&xlo[base + i * 8] = lb.q[i];
  }
}

// ---------------------------------------------------------------------------
// knn = r16 VERBATIM (best passing config, 278 us total / knn 206 us).
//   - register round-trip staging (race-free within the kernel)
//   - two barriers/tile; swapped-operand MFMA; selection on accumulators
//   - per-tile cap-2 EXEC-MASKED push buffer
// ---------------------------------------------------------------------------
__global__ __launch_bounds__(256, 3) void knn_kernel(
    const unsigned short* __restrict__ xhi, const unsigned short* __restrict__ xlo,
    const float* __restrict__ sq, float* __restrict__ pv, int* __restrict__ pi) {
  __shared__ struct { unsigned short bhi[64 * CP_]; unsigned short blo[64 * CP_]; } S; // 26624 B
  __shared__ float sqc[64];
  const int b = blockIdx.y, r0 = blockIdx.x * 64, h = blockIdx.z;
  const int tid = threadIdx.x;
  const int lane = tid & 63, w = tid >> 6;
  const int fp = lane & 15, kg = lane >> 4;
  const size_t bm = (size_t)b * M_;
  const int nbeg = h * NPART;

  // resident QUERY fragments (B operand): query q = r0 + w*16 + fp
  f16x8 qhi[3], qlo[3];
#pragma unroll
  for (int kt = 0; kt < 3; ++kt) {
    size_t off = (bm + r0 + w * 16 + fp) * CP_ + kt * 32 + kg * 8;
    qhi[kt] = *(const f16x8*)&xhi[off];
    qlo[kt] = *(const f16x8*)&xlo[off];
  }

  float tv[K_]; int ti[K_]; float tmax = 3.4e38f; int tpos = 0;
#pragma unroll
  for (int k = 0; k < K_; ++k) { tv[k] = 3.4e38f; ti[k] = 0; }

  // prefetch registers: 832 uint4 per array / 256 threads = 3 + (tid<64 ? 1:0)
  uint4 ph0, ph1, ph2, ph3, pl0, pl1, pl2, pl3;
  float sqreg = 0.f;
  auto gload = [&](int n0) {           // global -> private regs (no race class)
    const uint4* gh = (const uint4*)(xhi + (bm + n0) * CP_);
    const uint4* gl = (const uint4*)(xlo + (bm + n0) * CP_);
    ph0 = gh[tid]; ph1 = gh[tid + 256]; ph2 = gh[tid + 512];
    pl0 = gl[tid]; pl1 = gl[tid + 256]; pl2 = gl[tid + 512];
    if (tid < 64) {
      ph3 = gh[tid + 768]; pl3 = gl[tid + 768];
      sqreg = sq[bm + n0 + tid];
    }
  };
  auto swrite = [&]() {                // regs -> LDS (between the barrier pair)
    uint4* dh = (uint4*)S.bhi; uint4* dl = (uint4*)S.blo;
    dh[tid] = ph0; dh[tid + 256] = ph1; dh[tid + 512] = ph2;
    dl[tid] = pl0; dl[tid + 256] = pl1; dl[tid + 512] = pl2;
    if (tid < 64) { dh[tid + 768] = ph3; dl[tid + 768] = pl3; sqc[tid] = sqreg; }
  };

  gload(nbeg);
  for (int t = 0; t < NTILES; ++t) {
    const int n0 = nbeg + t * 64;
    __syncthreads();                   // all lanes done READING tile t-1 from S
    swrite();
    if (t < NTILES - 1) gload(n0 + 64);  // next tile -> regs, hidden under compute
    __syncthreads();                   // tile t visible in S

    // per-tile cap-2 deferred-insert buffer (reset here, drained below)
    float b0d = 0.f, b1d = 0.f; int b0n = 0, b1n = 0, bcnt = 0;

#pragma unroll
    for (int rs = 0; rs < 4; ++rs) {
      // A fragment: neighbor rows rs*16+fp, k-slice kg*8 from LDS
      f16x8 nh[3], nl[3];
#pragma unroll
      for (int kt = 0; kt < 3; ++kt) {
        int boff = (rs * 16 + fp) * CP_ + kt * 32 + kg * 8;
        nh[kt] = *(const f16x8*)&S.bhi[boff];
        nl[kt] = *(const f16x8*)&S.blo[boff];
      }
      f32x4 acc = {0.f, 0.f, 0.f, 0.f};
#pragma unroll
      for (int kt = 0; kt < 3; ++kt) {
        acc = __builtin_amdgcn_mfma_f32_16x16x32_f16(nh[kt], qhi[kt], acc, 0, 0, 0);
        acc = __builtin_amdgcn_mfma_f32_16x16x32_f16(nh[kt], qlo[kt], acc, 0, 0, 0);
        acc = __builtin_amdgcn_mfma_f32_16x16x32_f16(nl[kt], qhi[kt], acc, 0, 0, 0);
      }
      // D: col=lane&15 (our query), row=(lane>>4)*4+r (neighbor in chunk rs)
#pragma unroll
      for (int r = 0; r < 4; ++r) {
        const int nrow = rs * 16 + kg * 4 + r;
        const float d = sqc[nrow] - 2.f * acc[r];   // broadcast LDS read
        if (d < tmax) {
          const int n = n0 + nrow;
          if (bcnt == 2) {
            if (b0d < tmax) INSERT(b0d, b0n);   // recheck: tmax may have tightened
            b0d = b1d; b0n = b1n;
            b1d = d;   b1n = n;
          } else if (bcnt == 1) {
            b1d = d; b1n = n; bcnt = 2;
          } else {
            b0d = d; b0n = n; bcnt = 1;
          }
        }
      }
    }
    // end-of-tile drain (recheck each; b0 is older)
    if (bcnt >= 1 && b0d < tmax) INSERT(b0d, b0n);
    if (bcnt == 2 && b1d < tmax) INSERT(b1d, b1n);
  }

  // ---- merge 4 lane-lists (kg) per query row -> per-part top-9 -> ws ----
  __syncthreads();                     // tile reads done; reuse S as merge buf
  float* mv = (float*)&S;
  int*   mi = (int*)((char*)&S + 64 * 37 * 4);
  const int qrow = w * 16 + fp;
#pragma unroll
  for (int k = 0; k < K_; ++k) {
    mv[qrow * 37 + kg * K_ + k] = tv[k];
    mi[qrow * 37 + kg * K_ + k] = ti[k];
  }
  __syncthreads();
  if (tid < 64) {
    float fv[K_]; int fi[K_];
    float mx = 3.4e38f; int mp = 0;
#pragma unroll
    for (int k = 0; k < K_; ++k) { fv[k] = 3.4e38f; fi[k] = 0; }
    for (int s = 0; s < 36; ++s) {
      float v = mv[tid * 37 + s]; int id = mi[tid * 37 + s];
      if (v < mx) {
#pragma unroll
        for (int k = 0; k < K_; ++k) if (k == mp) { fv[k] = v; fi[k] = id; }
        float m2 = fv[0]; int p2 = 0;
#pragma unroll
        for (int k = 1; k < K_; ++k) if (fv[k] > m2) { m2 = fv[k]; p2 = k; }
        mx = m2; mp = p2;
      }
    }
    size_t base = ((size_t)h * B_ * M_ + bm + r0 + tid) * K_;
#pragma unroll
    for (int k = 0; k < K_; ++k) { pv[base + k] = fv[k]; pi[base + k] = fi[k]; }
  }
}

// ---------------------------------------------------------------------------
// knn_merge: top-9 of the two half-space top-9 lists -> idxw.
// ---------------------------------------------------------------------------
__global__ __launch_bounds__(256) void knn_merge_kernel(
    const float* __restrict__ pv, const int* __restrict__ pi,
    int* __restrict__ idxw) {
  const int g = blockIdx.x * 256 + threadIdx.x;        // 0 .. B_*M_-1
  float tv[K_]; int ti[K_]; float tmax = 3.4e38f; int tpos = 0;
#pragma unroll
  for (int k = 0; k < K_; ++k) { tv[k] = 3.4e38f; ti[k] = 0; }
#pragma unroll
  for (int h = 0; h < NSPLIT; ++h) {
    const float* vs = pv + ((size_t)h * B_ * M_ + g) * K_;
    const int*   is = pi + ((size_t)h * B_ * M_ + g) * K_;
#pragma unroll
    for (int s = 0; s < K_; ++s) {
      float d = vs[s];
      if (d < tmax) { int n = is[s]; INSERT(d, n); }
    }
  }
#pragma unroll
  for (int k = 0; k < K_; ++k) idxw[(size_t)g * K_ + k] = ti[k];
}

// ---------------------------------------------------------------------------
// prep2: P/Q projection GEMM.
//   P[m] = x_m @ (W1[0:C] - W1[C:2C]) + b1,  Q[m] = x_m @ W1[C:2C]
// ---------------------------------------------------------------------------
__global__ __launch_bounds__(256) void prep2_kernel(
    const float* __restrict__ x, const float* __restrict__ W1,
    const float* __restrict__ b1, float* __restrict__ P, float* __restrict__ Q) {
  __shared__ float Xt[C_][64];
  __shared__ float Wt[C_][64];
  const int b = blockIdx.y, m0 = blockIdx.x * 64;
  const int tid = threadIdx.x;
  const float* xb = x + (size_t)b * C_ * M_;

  for (int i = tid; i < C_ * 16; i += 256) {
    int c = i >> 4, j4 = (i & 15) << 2;
    *(float4*)&Xt[c][j4] = *(const float4*)&xb[(size_t)c * M_ + m0 + j4];
  }

  const int ty = tid >> 4, tx = tid & 15;
  for (int t = 0; t < 3; ++t) {
    const int u0 = t * 64;
    __syncthreads();
    for (int i = tid; i < C_ * 64; i += 256) {
      int cin = i >> 6, j = i & 63;
      int u = u0 + j;
      float wv;
      if (u < C_) wv = W1[cin * C_ + u] - W1[(C_ + cin) * C_ + u];
      else        wv = W1[(C_ + cin) * C_ + (u - C_)];
      Wt[cin][j] = wv;
    }
    __syncthreads();
    float acc[4][4] = {};
#pragma unroll 8
    for (int c = 0; c < C_; ++c) {
      float4 rr = *(const float4*)&Xt[c][ty << 2];
      float4 ww = *(const float4*)&Wt[c][tx << 2];
      acc[0][0] += rr.x * ww.x; acc[0][1] += rr.x * ww.y; acc[0][2] += rr.x * ww.z; acc[0][3] += rr.x * ww.w;
      acc[1][0] += rr.y * ww.x; acc[1][1] += rr.y * ww.y; acc[1][2] += rr.y * ww.z; acc[1][3] += rr.y * ww.w;
      acc[2][0] += rr.z * ww.x; acc[2][1] += rr.z * ww.y; acc[2][2] += rr.z * ww.z; acc[2][3] += rr.z * ww.w;
      acc[3][0] += rr.w * ww.x; acc[3][1] += rr.w * ww.y; acc[3][2] += rr.w * ww.z; acc[3][3] += rr.w * ww.w;
    }
#pragma unroll
    for (int i = 0; i < 4; ++i) {
      int m = m0 + (ty << 2) + i;
      size_t base = ((size_t)b * M_ + m) * C_;
#pragma unroll
      for (int j = 0; j < 4; ++j) {
        int u = u0 + (tx << 2) + j;
        float v = acc[i][j];
        if (u < C_) P[base + u] = v + b1[u];
        else        Q[base + (u - C_)] = v;
      }
    }
  }
}

// ---------------------------------------------------------------------------
// edge_mlp: g[m] = mean_k LReLU(P[m] + Q[idx[m,k]]); out = relu(g @ W2 + b2).
// ---------------------------------------------------------------------------
__global__ __launch_bounds__(256) void edge_mlp_kernel(
    const float* __restrict__ P, const float* __restrict__ Q,
    const int* __restrict__ idxw, const float* __restrict__ W2,
    const float* __restrict__ b2, float* __restrict__ out) {
  __shared__ float g_l[C_][64];
  __shared__ float W2t[C_ * C_];
  const int b = blockIdx.y, m0 = blockIdx.x * 64;
  const int tid = threadIdx.x;

  for (int i = tid; i < (C_ * C_) / 4; i += 256)
    *(float4*)&W2t[i * 4] = *(const float4*)&W2[i * 4];

  const int ml = tid & 63, cg = tid >> 6;
  const int m = m0 + ml;
  const float* prow = P + ((size_t)b * M_ + m) * C_ + cg * 24;
  float pr[24];
#pragma unroll
  for (int t = 0; t < 24; t += 4) {
    float4 v = *(const float4*)(prow + t);
    pr[t] = v.x; pr[t + 1] = v.y; pr[t + 2] = v.z; pr[t + 3] = v.w;
  }
  float gacc[24] = {};
  const int* irow = idxw + ((size_t)b * M_ + m) * K_;
#pragma unroll
  for (int k = 0; k < K_; ++k) {
    int j = irow[k];
    const float* qrow = Q + ((size_t)b * M_ + j) * C_ + cg * 24;
#pragma unroll
    for (int t = 0; t < 24; t += 4) {
      float4 qv = *(const float4*)(qrow + t);
      float h;
      h = pr[t + 0] + qv.x; gacc[t + 0] += (h >= 0.f) ? h : 0.01f * h;
      h = pr[t + 1] + qv.y; gacc[t + 1] += (h >= 0.f) ? h : 0.01f * h;
      h = pr[t + 2] + qv.z; gacc[t + 2] += (h >= 0.f) ? h : 0.01f * h;
      h = pr[t + 3] + qv.w; gacc[t + 3] += (h >= 0.f) ? h : 0.01f * h;
    }
  }
#pragma unroll
  for (int t = 0; t < 24; ++t) g_l[cg * 24 + t][ml] = gacc[t] * (1.f / 9.f);
  __syncthreads();

  const int ty = tid >> 4, tx = tid & 15;
  float acc2[4][6] = {};
#pragma unroll 4
  for (int c = 0; c < C_; ++c) {
    float4 rr = *(const float4*)&g_l[c][ty << 2];
    float2 wa = *(const float2*)&W2t[c * C_ + tx * 6];
    float2 wb = *(const float2*)&W2t[c * C_ + tx * 6 + 2];
    float2 wc = *(const float2*)&W2t[c * C_ + tx * 6 + 4];
    float rv[4] = {rr.x, rr.y, rr.z, rr.w};
    float wv[6] = {wa.x, wa.y, wb.x, wb.y, wc.x, wc.y};
#pragma unroll
    for (int i = 0; i < 4; ++i)
#pragma unroll
      for (int j = 0; j < 6; ++j) acc2[i][j] += rv[i] * wv[j];
  }
#pragma unroll
  for (int i = 0; i < 4; ++i) {
    int mm = m0 + (ty << 2) + i;
#pragma unroll
    for (int j = 0; j < 6; ++j) {
      int u = tx * 6 + j;
      float v = acc2[i][j] + b2[u];
      v = fmaxf(v, 0.f);
      out[((size_t)b * C_ + u) * M_ + mm] = v;
    }
  }
}

extern "C" void kernel_launch(void* const* d_in, const int* in_sizes, int n_in,
                              void* d_out, int out_size, void* d_ws, size_t ws_size,
                              hipStream_t stream) {
  const float* x  = (const float*)d_in[0];
  const float* W1 = (const float*)d_in[1];
  const float* b1 = (const float*)d_in[2];
  const float* W2 = (const float*)d_in[3];
  const float* b2 = (const float*)d_in[4];
  float* out = (float*)d_out;

  // Workspace: PREFER FULLY-DISJOINT layout (44,826,624 B); fall back to the
  // r16 aliased layout when ws_size is smaller. Host-side branch on ws_size
  // is deterministic across calls -> graph-safe. (Exact r20 source, which
  // passed post-timing validation at 278.6 us.)
  char* ws = (char*)d_ws;
  float* sq  = (float*)ws;                       // [0, 131072)
  int* idxw  = (int*)(ws + 131072);              // [131072, 1310720)
  unsigned short* xhi = (unsigned short*)(ws + 1310720);   // 6,815,744 B
  unsigned short* xlo = (unsigned short*)(ws + 8126464);   // 6,815,744 B
  float* pv; int* pi; float* P; float* Q;
  if (ws_size >= 44826624u) {
    pv = (float*)(ws + 14942208);                // 2,359,296 B
    pi = (int*)(ws + 17301504);                  // 2,359,296 B
    P  = (float*)(ws + 19660800);                // 12,582,912 B
    Q  = (float*)(ws + 32243712);                // 12,582,912 B  (end 44,826,624)
  } else {
    // r16 fallback (aliased; passed validation at 278 us)
    pv = (float*)(ws + 14942208);
    pi = (int*)(ws + 19660800);
    P  = (float*)(ws + 1310720);
    Q  = (float*)(ws + 13893632);
  }

  dim3 blk(256);
  prep1_kernel<<<dim3(M_ / 64, B_), blk, 0, stream>>>(x, sq, xhi, xlo);
  knn_kernel<<<dim3(M_ / 64, B_, NSPLIT), blk, 0, stream>>>(xhi, xlo, sq, pv, pi);
  knn_merge_kernel<<<dim3(B_ * M_ / 256), blk, 0, stream>>>(pv, pi, idxw);
  prep2_kernel<<<dim3(M_ / 64, B_), blk, 0, stream>>>(x, W1, b1, P, Q);
  edge_mlp_kernel<<<dim3(M_ / 64, B_), blk, 0, stream>>>(P, Q, idxw, W2, b2, out);
}